// Round 2
// baseline (246.108 us; speedup 1.0000x reference)
//
#include <hip/hip_runtime.h>
#include <math.h>

#define NQ 512
#define NC 8000
#define DNUM 6
#define NBINS 50
#define DCAT 20
#define DENC 26      // DNUM + DCAT
#define DOUT 10
#define CHUNK 1000
#define NCHUNK 8
#define NQP 256      // query pairs
#define CPH 4        // chunks per half-block
#define PPITCH 24    // floats per (qpair,half) partial record

// ---------- encode ----------
// G_f(v) = sum_j ceil((v - u_fj*delta_fj)/delta_fj). Each per-bin map is
// fp-monotone in v (sub, div-by-positive, ceil), so all 50 bin diffs for a
// feature share sign => sum_j |bin_j(x)-bin_j(c)| == |G_f(x)-G_f(c)| exactly
// (integer-valued floats, sums << 2^24). 320-dim L1 -> 26-dim L1.
// Also zeroes the 256 combine counters each launch (workspace is re-poisoned
// by the harness before every iteration, so nca's atomic counters MUST be
// re-initialized here, upstream of nca in stream order).
__global__ void encode(const float* __restrict__ c_num, const float* __restrict__ c_cat,
                       const float* __restrict__ x_num, const float* __restrict__ x_cat,
                       const float* __restrict__ delta, const float* __restrict__ u,
                       float* __restrict__ cEnc, float* __restrict__ qEnc,
                       int* __restrict__ counters) {
    int i = blockIdx.x * 256 + threadIdx.x;
    if (i < NQP) counters[i] = 0;
    const int nA = (NC + NQ) * DNUM;          // 51072
    const int nB = (NC + NQ) * DCAT;          // 170240
    if (i < nA) {
        int f = i % DNUM, p = i / DNUM;
        bool is_c = p < NC;
        int idx = is_c ? p : p - NC;
        float v = (is_c ? c_num : x_num)[idx * DNUM + f];
        float g = 0.f;
        for (int j = 0; j < NBINS; ++j) {
            // exact reference op order: scaled_u = u*delta; ceil((v - sc)/delta)
            float dl = delta[f * NBINS + j];
            float sc = u[f * NBINS + j] * dl;
            g += ceilf((v - sc) / dl);
        }
        if (is_c) cEnc[f * NC + idx] = g;
        else      qEnc[f * NQ + idx] = g;
    } else if (i < nA + nB) {
        int i2 = i - nA;
        int k = i2 % DCAT, p = i2 / DCAT;
        bool is_c = p < NC;
        int idx = is_c ? p : p - NC;
        float v = (is_c ? c_cat : x_cat)[idx * DCAT + k];
        if (is_c) cEnc[(DNUM + k) * NC + idx] = v;
        else      qEnc[(DNUM + k) * NQ + idx] = v;
    }
}

// ---------- nca, chunk-split ----------
// ROUND-2 THEORY: round-1's fused+ping-pong kernel spilled (VGPR=100 reported
// vs ~200 live => scratch; 110us @ VALUBusy 10%). Revert to the verified
// round-0 body; attack latency instead of traffic: 512 blocks, each = the
// SAME 2 queries x HALF the chunks (4). Total L2 traffic unchanged (213 MB),
// but 2 blocks/CU -> 4 waves/SIMD (vs 2) for latency hiding. VGPR kept <=128
// (launch_bounds(512,4)) by streaming cv in two 13-dim passes per chunk
// (identical fp accumulation order d=0..25). Halves meet via a last-arriver
// atomic combine: logits AND per-chunk-lse are additive across halves
// (reference SUMS per-chunk logsumexp), so combine = add partials + final log.
// No spin, no co-residency assumption: works at any occupancy.
__global__ __launch_bounds__(512, 4) void nca_half(
    const float* __restrict__ cEnc, const float* __restrict__ qEnc,
    const int* __restrict__ cy, float* __restrict__ pPart,
    int* __restrict__ counters, float* __restrict__ out) {
    __shared__ float xs[DENC * 2];              // 52
    __shared__ float ms_parts[CPH * 8 * 4];     // [lc][wave][m0,s0,m1,s1]
    __shared__ float cls_parts[8][2 * DOUT];    // [wave][q*10+k]
    __shared__ float tmp[2][CPH];
    __shared__ float lse_sh[2];
    __shared__ int amLast;

    const int tid = threadIdx.x;
    const int qp = blockIdx.x >> 1;
    const int half = blockIdx.x & 1;
    const int q0 = qp * 2;

    if (tid < DENC * 2) {
        int d = tid >> 1, q = tid & 1;
        xs[tid] = qEnc[d * NQ + q0 + q];
    }
    __syncthreads();

    // queries -> registers (no in-loop LDS reads)
    float xr0[DENC], xr1[DENC];
#pragma unroll
    for (int d = 0; d < DENC; ++d) { xr0[d] = xs[2 * d]; xr1[d] = xs[2 * d + 1]; }

    const bool act = tid < 500;                 // 500 * 2 = 1000 candidates
    const int cl = act ? 2 * tid : 996;         // clamp inactive to safe addr
    const int lane = tid & 63, wave = tid >> 6;

    float cls[2 * DOUT];                        // per-thread class sums (4 chunks)
#pragma unroll
    for (int k = 0; k < 2 * DOUT; ++k) cls[k] = 0.f;

    for (int lc = 0; lc < CPH; ++lc) {
        const int c = half * CPH + lc;
        const float* cp = cEnc + (size_t)c * CHUNK + cl;
        float a00 = 0.f, a01 = 0.f, a10 = 0.f, a11 = 0.f;   // a[q][cand]

        // two 13-dim passes: halves cv register footprint (VGPR<=128 for
        // 2 blocks/CU); accumulation order d=0..25 identical to round-0.
        float2 cv[13];
#pragma unroll
        for (int d = 0; d < 13; ++d) cv[d] = *(const float2*)(cp + (size_t)d * NC);
#pragma unroll
        for (int d = 0; d < 13; ++d) {
            a00 += fabsf(cv[d].x - xr0[d]); a01 += fabsf(cv[d].y - xr0[d]);
            a10 += fabsf(cv[d].x - xr1[d]); a11 += fabsf(cv[d].y - xr1[d]);
        }
#pragma unroll
        for (int d = 0; d < 13; ++d) cv[d] = *(const float2*)(cp + (size_t)(13 + d) * NC);
#pragma unroll
        for (int d = 0; d < 13; ++d) {
            a00 += fabsf(cv[d].x - xr0[13 + d]); a01 += fabsf(cv[d].y - xr0[13 + d]);
            a10 += fabsf(cv[d].x - xr1[13 + d]); a11 += fabsf(cv[d].y - xr1[13 + d]);
        }

        // wave-local min per q (lse partial)
        float m0 = act ? fminf(a00, a01) : INFINITY;
        float m1 = act ? fminf(a10, a11) : INFINITY;
#pragma unroll
        for (int sh = 32; sh >= 1; sh >>= 1) {
            m0 = fminf(m0, __shfl_xor(m0, sh));
            m1 = fminf(m1, __shfl_xor(m1, sh));
        }

        int2 y = *(const int2*)(cy + (size_t)c * CHUNK + cl);
        float s0 = 0.f, s1 = 0.f;
        if (act) {
            float e00 = __expf(-a00), e01 = __expf(-a01);
            float e10 = __expf(-a10), e11 = __expf(-a11);
            s0 = __expf(m0 - a00) + __expf(m0 - a01);
            s1 = __expf(m1 - a10) + __expf(m1 - a11);
#pragma unroll
            for (int k = 0; k < DOUT; ++k) {
                // mask in {0,1}: fma is bit-identical to select+add (verified r1)
                float mx = (y.x == k) ? 1.f : 0.f;
                float my = (y.y == k) ? 1.f : 0.f;
                cls[k]        = fmaf(mx, e00, fmaf(my, e01, cls[k]));
                cls[DOUT + k] = fmaf(mx, e10, fmaf(my, e11, cls[DOUT + k]));
            }
        }
#pragma unroll
        for (int sh = 32; sh >= 1; sh >>= 1) {
            s0 += __shfl_xor(s0, sh);
            s1 += __shfl_xor(s1, sh);
        }
        if (lane == 0) {
            float* p = ms_parts + (lc * 8 + wave) * 4;
            p[0] = m0; p[1] = s0; p[2] = m1; p[3] = s1;
        }
    }

    // one butterfly for the 20 class sums
#pragma unroll
    for (int k = 0; k < 2 * DOUT; ++k) {
#pragma unroll
        for (int sh = 32; sh >= 1; sh >>= 1) cls[k] += __shfl_xor(cls[k], sh);
    }
    if (lane == 0) {
#pragma unroll
        for (int k = 0; k < 2 * DOUT; ++k) cls_parts[wave][k] = cls[k];
    }
    __syncthreads();

    // per-(q,local-chunk) lse: combine 8 wave partials exactly
    if (tid < 2 * CPH) {
        int q = tid & 1, ch = tid >> 1;
        const float* p = ms_parts + ch * 32 + 2 * q;
        float M = INFINITY;
#pragma unroll
        for (int w = 0; w < 8; ++w) M = fminf(M, p[w * 4]);
        float S = 0.f;
#pragma unroll
        for (int w = 0; w < 8; ++w) S += __expf(M - p[w * 4]) * p[w * 4 + 1];
        tmp[q][ch] = logf(S) - M;     // log(sum_c exp(-d)) for this chunk
    }
    __syncthreads();
    if (tid < 2) {
        float l = 0.f;
#pragma unroll
        for (int ch = 0; ch < CPH; ++ch) l += tmp[tid][ch];   // local chunk order
        lse_sh[tid] = l;
    }
    __syncthreads();

    // write this half's partial record: [0..19]=class sums, [20..21]=lse(q0,q1)
    float* myPart = pPart + (size_t)(qp * 2 + half) * PPITCH;
    if (tid < 2 * DOUT) {
        float s = 0.f;
#pragma unroll
        for (int w = 0; w < 8; ++w) s += cls_parts[w][tid];
        myPart[tid] = s;
    }
    if (tid == 20 || tid == 21) myPart[tid] = lse_sh[tid - 20];
    __threadfence();            // release: partials visible device-wide
    __syncthreads();
    if (tid == 0) amLast = (atomicAdd(&counters[qp], 1) == 1);
    __syncthreads();
    if (amLast) {
        __threadfence();        // acquire: partner's fenced writes now visible
        if (tid < 2 * DOUT) {
            int q = tid / DOUT, k = tid % DOUT;
            const float* pa = pPart + (size_t)(qp * 2) * PPITCH;
            const float* pb = pPart + (size_t)(qp * 2 + 1) * PPITCH;
            float s = pa[tid] + pb[tid];
            float l = pa[20 + q] + pb[20 + q];
            out[(q0 + q) * DOUT + k] = logf(s + 1e-8f) - l;
        }
    }
}

extern "C" void kernel_launch(void* const* d_in, const int* in_sizes, int n_in,
                              void* d_out, int out_size, void* d_ws, size_t ws_size,
                              hipStream_t stream) {
    const float* x_num = (const float*)d_in[0];
    const float* x_cat = (const float*)d_in[1];
    const float* c_num = (const float*)d_in[2];
    const float* c_cat = (const float*)d_in[3];
    const int*   c_y   = (const int*)d_in[4];
    const float* delta = (const float*)d_in[5];
    const float* u     = (const float*)d_in[6];

    float* ws = (float*)d_ws;
    float* cEnc = ws;                                   // 26*8000 = 208,000 f
    float* qEnc = cEnc + (size_t)DENC * NC;             // 26*512  = 13,312 f
    float* pPart = qEnc + (size_t)DENC * NQ;            // 256*2*24 = 12,288 f
    int*   counters = (int*)(pPart + (size_t)NQP * 2 * PPITCH);  // 256 int

    const int total = (NC + NQ) * DENC;                 // 221,312
    encode<<<(total + 255) / 256, 256, 0, stream>>>(
        c_num, c_cat, x_num, x_cat, delta, u, cEnc, qEnc, counters);
    nca_half<<<NQP * 2, 512, 0, stream>>>(cEnc, qEnc, c_y, pPart, counters,
                                          (float*)d_out);
}

// Round 3
// 151.603 us; speedup vs baseline: 1.6234x; 1.6234x over previous
//
#include <hip/hip_runtime.h>
#include <math.h>

#define NQ 512
#define NC 8000
#define DNUM 6
#define NBINS 50
#define DCAT 20
#define DENC 26      // DNUM + DCAT
#define DOUT 10
#define CHUNK 1000
#define NCHUNK 8
#define NQUAD 128    // query quads (4 queries each)
#define QPB 4        // queries per block
#define CPH 500      // candidates per half (per chunk)
#define PPITCH 104   // per-(quad,half) record: 40 class + 8ch*4q*(m,s)=64

// ---------- encode ----------
// G_f(v) = sum_j ceil((v - u_fj*delta_fj)/delta_fj). Each per-bin map is
// fp-monotone in v (sub, div-by-positive, ceil), so all 50 bin diffs for a
// feature share sign => sum_j |bin_j(x)-bin_j(c)| == |G_f(x)-G_f(c)| exactly
// (integer-valued floats, sums << 2^24). 320-dim L1 -> 26-dim L1.
// Also zeroes the 128 combine counters each launch (workspace is re-poisoned
// by the harness before every iteration; counters MUST be re-initialized
// upstream of nca in stream order).
__global__ void encode(const float* __restrict__ c_num, const float* __restrict__ c_cat,
                       const float* __restrict__ x_num, const float* __restrict__ x_cat,
                       const float* __restrict__ delta, const float* __restrict__ u,
                       float* __restrict__ cEnc, float* __restrict__ qEnc,
                       int* __restrict__ counters) {
    int i = blockIdx.x * 256 + threadIdx.x;
    if (i < NQUAD) counters[i] = 0;
    const int nA = (NC + NQ) * DNUM;          // 51072
    const int nB = (NC + NQ) * DCAT;          // 170240
    if (i < nA) {
        int f = i % DNUM, p = i / DNUM;
        bool is_c = p < NC;
        int idx = is_c ? p : p - NC;
        float v = (is_c ? c_num : x_num)[idx * DNUM + f];
        float g = 0.f;
        for (int j = 0; j < NBINS; ++j) {
            // exact reference op order: scaled_u = u*delta; ceil((v - sc)/delta)
            float dl = delta[f * NBINS + j];
            float sc = u[f * NBINS + j] * dl;
            g += ceilf((v - sc) / dl);
        }
        if (is_c) cEnc[f * NC + idx] = g;
        else      qEnc[f * NQ + idx] = g;
    } else if (i < nA + nB) {
        int i2 = i - nA;
        int k = i2 % DCAT, p = i2 / DCAT;
        bool is_c = p < NC;
        int idx = is_c ? p : p - NC;
        float v = (is_c ? c_cat : x_cat)[idx * DCAT + k];
        if (is_c) cEnc[(DNUM + k) * NC + idx] = v;
        else      qEnc[(DNUM + k) * NQ + idx] = v;
    }
}

// ---------- nca: query-quad x candidate-half ----------
// ROUND-3 THEORY: round-0's nca is L2-BW-bound (256 blocks x 832 KB cEnc =
// 213 MB @ ~34.5 TB/s ~ 6.4 us floor; VALU only ~2 us). Double the query
// reuse per byte: 256 blocks = 128 quads x 2 candidate-halves; each block
// reads 4000 cands x 26 dims = 416 KB -> total 107 MB (halved). Same total
// VALU, same block count. 1 candidate/thread, scalar coalesced loads.
// REGISTER RULE (paid twice in r1/r2): plain __launch_bounds__(512), NO
// min-waves arg — compiler free to 256 VGPR at 1 block/CU, the only
// verified no-spill regime for this body. xr loads have wave-uniform
// addresses -> compiler may scalarize to SGPR.
// Cross-half combine: per-chunk per-q (m,s) merged exactly
// (M=min(mA,mB), S=exp(M-mA)sA+exp(M-mB)sB, lse_ch=log(S)-M); class sums
// additive. Last-arriver atomic combine: release fence -> atomicAdd ->
// acquire fence; no spin, no co-residency assumption.
__global__ __launch_bounds__(512) void nca_quad(
    const float* __restrict__ cEnc, const float* __restrict__ qEnc,
    const int* __restrict__ cy, float* __restrict__ pPart,
    int* __restrict__ counters, float* __restrict__ out) {
    __shared__ float ms_parts[NCHUNK][8][2 * QPB];  // [ch][wave][q*2+{m,s}]
    __shared__ float cls_parts[8][QPB * DOUT];      // [wave][q*10+k]
    __shared__ int amLast;

    const int tid = threadIdx.x;
    const int quad = blockIdx.x >> 1;
    const int half = blockIdx.x & 1;
    const int q0 = quad * QPB;

    // queries -> registers via wave-uniform loads (scalarizable)
    float xr[QPB][DENC];
#pragma unroll
    for (int q = 0; q < QPB; ++q)
#pragma unroll
        for (int d = 0; d < DENC; ++d)
            xr[q][d] = qEnc[d * NQ + q0 + q];

    const bool act = tid < CPH;                 // 500 candidates per half
    const int cidx = half * CPH + (act ? tid : CPH - 1);  // clamp to safe addr
    const int lane = tid & 63, wave = tid >> 6;

    float cls[QPB * DOUT];                      // per-thread class sums
#pragma unroll
    for (int k = 0; k < QPB * DOUT; ++k) cls[k] = 0.f;

    for (int ch = 0; ch < NCHUNK; ++ch) {
        const float* cp = cEnc + (size_t)ch * CHUNK + cidx;
        float a[QPB] = {0.f, 0.f, 0.f, 0.f};
#pragma unroll
        for (int d = 0; d < DENC; ++d) {
            float c = cp[(size_t)d * NC];       // coalesced dword, L2-resident
#pragma unroll
            for (int q = 0; q < QPB; ++q) a[q] += fabsf(c - xr[q][d]);
        }

        // wave-local min per q (lse partial, max-shift base)
        float m[QPB];
#pragma unroll
        for (int q = 0; q < QPB; ++q) m[q] = act ? a[q] : INFINITY;
#pragma unroll
        for (int sh = 32; sh >= 1; sh >>= 1)
#pragma unroll
            for (int q = 0; q < QPB; ++q) m[q] = fminf(m[q], __shfl_xor(m[q], sh));

        int y = cy[(size_t)ch * CHUNK + cidx];
        float s[QPB] = {0.f, 0.f, 0.f, 0.f};
        if (act) {
#pragma unroll
            for (int q = 0; q < QPB; ++q) {
                float e = __expf(-a[q]);
                s[q] = __expf(m[q] - a[q]);
#pragma unroll
                for (int k = 0; k < DOUT; ++k) {
                    // mask in {0,1}: fma bit-identical to select+add (r1-verified)
                    float mk = (y == k) ? 1.f : 0.f;
                    cls[q * DOUT + k] = fmaf(mk, e, cls[q * DOUT + k]);
                }
            }
        }
#pragma unroll
        for (int sh = 32; sh >= 1; sh >>= 1)
#pragma unroll
            for (int q = 0; q < QPB; ++q) s[q] += __shfl_xor(s[q], sh);
        if (lane == 0) {
#pragma unroll
            for (int q = 0; q < QPB; ++q) {
                ms_parts[ch][wave][q * 2]     = m[q];
                ms_parts[ch][wave][q * 2 + 1] = s[q];
            }
        }
    }

    // one butterfly for the 40 class sums
#pragma unroll
    for (int k = 0; k < QPB * DOUT; ++k)
#pragma unroll
        for (int sh = 32; sh >= 1; sh >>= 1) cls[k] += __shfl_xor(cls[k], sh);
    if (lane == 0) {
#pragma unroll
        for (int k = 0; k < QPB * DOUT; ++k) cls_parts[wave][k] = cls[k];
    }
    __syncthreads();

    // this half's partial record
    float* myPart = pPart + (size_t)(quad * 2 + half) * PPITCH;

    // per-(chunk,q): merge 8 wave partials exactly -> block (M,S)
    if (tid < NCHUNK * QPB) {                   // 32 threads
        int ch = tid >> 2, q = tid & 3;
        float M = INFINITY;
#pragma unroll
        for (int w = 0; w < 8; ++w) M = fminf(M, ms_parts[ch][w][q * 2]);
        float S = 0.f;
#pragma unroll
        for (int w = 0; w < 8; ++w)
            S += __expf(M - ms_parts[ch][w][q * 2]) * ms_parts[ch][w][q * 2 + 1];
        myPart[QPB * DOUT + ch * 8 + q * 2]     = M;
        myPart[QPB * DOUT + ch * 8 + q * 2 + 1] = S;
    }
    // class partials: sum 8 waves
    if (tid < QPB * DOUT) {                     // 40 threads
        float sum = 0.f;
#pragma unroll
        for (int w = 0; w < 8; ++w) sum += cls_parts[w][tid];
        myPart[tid] = sum;
    }
    __threadfence();            // release: partials visible device-wide
    __syncthreads();
    if (tid == 0) amLast = (atomicAdd(&counters[quad], 1) == 1);
    __syncthreads();
    if (amLast) {
        __threadfence();        // acquire: partner's fenced writes visible
        if (tid < QPB * DOUT) {
            int q = tid / DOUT, k = tid % DOUT;
            const float* pa = pPart + (size_t)(quad * 2) * PPITCH;
            const float* pb = pPart + (size_t)(quad * 2 + 1) * PPITCH;
            float sum = pa[tid] + pb[tid];
            float l = 0.f;
#pragma unroll
            for (int ch = 0; ch < NCHUNK; ++ch) {   // chunk order = reference
                float mA = pa[QPB * DOUT + ch * 8 + q * 2];
                float sA = pa[QPB * DOUT + ch * 8 + q * 2 + 1];
                float mB = pb[QPB * DOUT + ch * 8 + q * 2];
                float sB = pb[QPB * DOUT + ch * 8 + q * 2 + 1];
                float M = fminf(mA, mB);
                float S = __expf(M - mA) * sA + __expf(M - mB) * sB;
                l += logf(S) - M;   // log(sum_c exp(-d)) for this chunk
            }
            out[(q0 + q) * DOUT + k] = logf(sum + 1e-8f) - l;
        }
    }
}

extern "C" void kernel_launch(void* const* d_in, const int* in_sizes, int n_in,
                              void* d_out, int out_size, void* d_ws, size_t ws_size,
                              hipStream_t stream) {
    const float* x_num = (const float*)d_in[0];
    const float* x_cat = (const float*)d_in[1];
    const float* c_num = (const float*)d_in[2];
    const float* c_cat = (const float*)d_in[3];
    const int*   c_y   = (const int*)d_in[4];
    const float* delta = (const float*)d_in[5];
    const float* u     = (const float*)d_in[6];

    float* ws = (float*)d_ws;
    float* cEnc = ws;                                   // 26*8000 = 208,000 f
    float* qEnc = cEnc + (size_t)DENC * NC;             // 26*512  = 13,312 f
    float* pPart = qEnc + (size_t)DENC * NQ;            // 128*2*104 = 26,624 f
    int*   counters = (int*)(pPart + (size_t)NQUAD * 2 * PPITCH);  // 128 int

    const int total = (NC + NQ) * DENC;                 // 221,312
    encode<<<(total + 255) / 256, 256, 0, stream>>>(
        c_num, c_cat, x_num, x_cat, delta, u, cEnc, qEnc, counters);
    nca_quad<<<NQUAD * 2, 512, 0, stream>>>(cEnc, qEnc, c_y, pPart, counters,
                                            (float*)d_out);
}

// Round 4
// 93.451 us; speedup vs baseline: 2.6335x; 1.6223x over previous
//
#include <hip/hip_runtime.h>
#include <math.h>

#define NQ 512
#define NC 8000
#define DNUM 6
#define NBINS 50
#define DCAT 20
#define DENC 26      // DNUM + DCAT
#define DOUT 10
#define CHUNK 1000
#define NCHUNK 8

// ============================================================================
// ROUND-4: verbatim revert to the round-0 kernel (verified 92.4/93.0 us).
//
// Session ledger (why this exact form):
//  r1 fused+ping-pong:       110 us — VGPR=100 < ~200 live -> scratch spill.
//  r2 chunk-split (512,4):   193 us — min-waves bound -> VGPR=64, 130 MB
//                            WRITE_SIZE of spill stores.
//  r3 quad+uniform loads:     85 us — VGPR=56/SGPR=112: wave-uniform qEnc
//                            reads scalarized to s_load, rematerialized in
//                            the inner loop -> scalar-unit latency bound.
//  DO NOT: add a min-waves launch bound; hold >1 chunk of candidates in
//  registers; or read query values via wave-uniform global loads. Queries
//  MUST go global -> LDS -> per-lane VGPR (ds_read results stay resident).
//
// Remaining ceiling (why no further attempt): timed region = 2 x 40.2 us
// harness poison fills (256 MiB @ 6.66 TB/s = 83% HBM peak, unremovable)
// + ~12.6 us ours (encode ~2.5 + nca ~9 + gaps). nca's L2-BW floor:
// 256 blocks x 832 KB = 213 MB @ ~34.5 TB/s ~ 6.4 us. Total headroom <= 4%.
// ============================================================================

// ---------- encode ----------
// G_f(v) = sum_j ceil((v - u_fj*delta_fj)/delta_fj). Each per-bin map is
// fp-monotone in v (sub, div-by-positive, ceil), so all 50 bin diffs for a
// feature share sign => sum_j |bin_j(x)-bin_j(c)| == |G_f(x)-G_f(c)| exactly
// (integer-valued floats, sums << 2^24). 320-dim L1 -> 26-dim L1.
__global__ void encode(const float* __restrict__ c_num, const float* __restrict__ c_cat,
                       const float* __restrict__ x_num, const float* __restrict__ x_cat,
                       const float* __restrict__ delta, const float* __restrict__ u,
                       float* __restrict__ cEnc, float* __restrict__ qEnc) {
    int i = blockIdx.x * 256 + threadIdx.x;
    const int nA = (NC + NQ) * DNUM;          // 51072
    const int nB = (NC + NQ) * DCAT;          // 170240
    if (i < nA) {
        int f = i % DNUM, p = i / DNUM;
        bool is_c = p < NC;
        int idx = is_c ? p : p - NC;
        float v = (is_c ? c_num : x_num)[idx * DNUM + f];
        float g = 0.f;
        for (int j = 0; j < NBINS; ++j) {
            // exact reference op order: scaled_u = u*delta; ceil((v - sc)/delta)
            float dl = delta[f * NBINS + j];
            float sc = u[f * NBINS + j] * dl;
            g += ceilf((v - sc) / dl);
        }
        if (is_c) cEnc[f * NC + idx] = g;
        else      qEnc[f * NQ + idx] = g;
    } else if (i < nA + nB) {
        int i2 = i - nA;
        int k = i2 % DCAT, p = i2 / DCAT;
        bool is_c = p < NC;
        int idx = is_c ? p : p - NC;
        float v = (is_c ? c_cat : x_cat)[idx * DCAT + k];
        if (is_c) cEnc[(DNUM + k) * NC + idx] = v;
        else      qEnc[(DNUM + k) * NQ + idx] = v;
    }
}

// ---------- all-in-one: block = 2 queries x all 8000 candidates ----------
// grid 256 x 512 (1 block/CU). Class sums accumulate per-thread in registers
// across ALL chunks (one end-of-kernel butterfly); chunk loop keeps only the
// 4 lse chains; query values live in registers via LDS->per-lane reads.
__global__ __launch_bounds__(512) void nca_all(
    const float* __restrict__ cEnc, const float* __restrict__ qEnc,
    const int* __restrict__ cy, float* __restrict__ out) {
    __shared__ float xs[DENC * 2];              // 52
    __shared__ float ms_parts[NCHUNK * 8 * 4];  // [chunk][wave][m0,s0,m1,s1]
    __shared__ float cls_parts[8][2 * DOUT];    // [wave][q*10+k]
    __shared__ float tmp[2][NCHUNK];
    __shared__ float lse_sh[2];

    const int tid = threadIdx.x;
    const int q0 = blockIdx.x * 2;
    if (tid < DENC * 2) {
        int d = tid >> 1, q = tid & 1;
        xs[tid] = qEnc[d * NQ + q0 + q];
    }
    __syncthreads();

    // queries -> registers (kills in-loop LDS reads; ds_read results are
    // VGPR-resident — the allocator cannot scalarize/rematerialize them)
    float xr0[DENC], xr1[DENC];
#pragma unroll
    for (int d = 0; d < DENC; ++d) { xr0[d] = xs[2 * d]; xr1[d] = xs[2 * d + 1]; }

    const bool act = tid < 500;                 // 500 * 2 = 1000 candidates
    const int cl = act ? 2 * tid : 996;         // clamp inactive to safe addr
    const int lane = tid & 63, wave = tid >> 6;

    float cls[2 * DOUT];                        // per-thread class sums, all chunks
#pragma unroll
    for (int k = 0; k < 2 * DOUT; ++k) cls[k] = 0.f;

    for (int chunk = 0; chunk < NCHUNK; ++chunk) {
        const float* cp = cEnc + chunk * CHUNK + cl;
        float2 cv[DENC];
#pragma unroll
        for (int d = 0; d < DENC; ++d) cv[d] = *(const float2*)(cp + (size_t)d * NC);

        float a00 = 0.f, a01 = 0.f, a10 = 0.f, a11 = 0.f;   // a[q][cand]
#pragma unroll
        for (int d = 0; d < DENC; ++d) {
            a00 += fabsf(cv[d].x - xr0[d]); a01 += fabsf(cv[d].y - xr0[d]);
            a10 += fabsf(cv[d].x - xr1[d]); a11 += fabsf(cv[d].y - xr1[d]);
        }

        // wave-local min per q (lse partial)
        float m0 = act ? fminf(a00, a01) : INFINITY;
        float m1 = act ? fminf(a10, a11) : INFINITY;
#pragma unroll
        for (int sh = 32; sh >= 1; sh >>= 1) {
            m0 = fminf(m0, __shfl_xor(m0, sh));
            m1 = fminf(m1, __shfl_xor(m1, sh));
        }

        int2 y = *(const int2*)(cy + chunk * CHUNK + cl);
        float s0 = 0.f, s1 = 0.f;
        if (act) {
            float e00 = __expf(-a00), e01 = __expf(-a01);
            float e10 = __expf(-a10), e11 = __expf(-a11);
            s0 = __expf(m0 - a00) + __expf(m0 - a01);
            s1 = __expf(m1 - a10) + __expf(m1 - a11);
            // class sums accumulate in registers across chunks
#pragma unroll
            for (int k = 0; k < DOUT; ++k) {
                cls[k]        += (y.x == k ? e00 : 0.f) + (y.y == k ? e01 : 0.f);
                cls[DOUT + k] += (y.x == k ? e10 : 0.f) + (y.y == k ? e11 : 0.f);
            }
        }
#pragma unroll
        for (int sh = 32; sh >= 1; sh >>= 1) {
            s0 += __shfl_xor(s0, sh);
            s1 += __shfl_xor(s1, sh);
        }
        if (lane == 0) {
            float* p = ms_parts + (chunk * 8 + wave) * 4;
            p[0] = m0; p[1] = s0; p[2] = m1; p[3] = s1;
        }
    }

    // one butterfly for the 20 class sums
#pragma unroll
    for (int k = 0; k < 2 * DOUT; ++k) {
#pragma unroll
        for (int sh = 32; sh >= 1; sh >>= 1) cls[k] += __shfl_xor(cls[k], sh);
    }
    if (lane == 0) {
#pragma unroll
        for (int k = 0; k < 2 * DOUT; ++k) cls_parts[wave][k] = cls[k];
    }
    __syncthreads();

    // per-(q,chunk) lse: combine 8 wave partials exactly
    if (tid < 16) {
        int q = tid & 1, ch = tid >> 1;
        const float* p = ms_parts + ch * 32 + 2 * q;
        float M = INFINITY;
#pragma unroll
        for (int w = 0; w < 8; ++w) M = fminf(M, p[w * 4]);
        float S = 0.f;
#pragma unroll
        for (int w = 0; w < 8; ++w) S += __expf(M - p[w * 4]) * p[w * 4 + 1];
        tmp[q][ch] = logf(S) - M;     // log(sum_c exp(-d)) for this chunk
    }
    __syncthreads();
    if (tid < 2) {
        float l = 0.f;
#pragma unroll
        for (int ch = 0; ch < NCHUNK; ++ch) l += tmp[tid][ch];
        lse_sh[tid] = l;
    }
    __syncthreads();
    if (tid < 2 * DOUT) {
        int q = tid / DOUT, k = tid % DOUT;
        float s = 0.f;
#pragma unroll
        for (int w = 0; w < 8; ++w) s += cls_parts[w][q * DOUT + k];
        out[(q0 + q) * DOUT + k] = logf(s + 1e-8f) - lse_sh[q];
    }
}

extern "C" void kernel_launch(void* const* d_in, const int* in_sizes, int n_in,
                              void* d_out, int out_size, void* d_ws, size_t ws_size,
                              hipStream_t stream) {
    const float* x_num = (const float*)d_in[0];
    const float* x_cat = (const float*)d_in[1];
    const float* c_num = (const float*)d_in[2];
    const float* c_cat = (const float*)d_in[3];
    const int*   c_y   = (const int*)d_in[4];
    const float* delta = (const float*)d_in[5];
    const float* u     = (const float*)d_in[6];

    float* ws = (float*)d_ws;
    float* cEnc = ws;                             // 26*8000 = 208,000 floats
    float* qEnc = cEnc + (size_t)DENC * NC;       // 26*512  = 13,312

    const int total = (NC + NQ) * DENC;           // 221,312
    encode<<<(total + 255) / 256, 256, 0, stream>>>(
        c_num, c_cat, x_num, x_cat, delta, u, cEnc, qEnc);
    nca_all<<<NQ / 2, 512, 0, stream>>>(cEnc, qEnc, c_y, (float*)d_out);
}